// Round 19
// baseline (123.146 us; speedup 1.0000x reference)
//
#include <hip/hip_runtime.h>

typedef unsigned short u16;
typedef unsigned int u32;
typedef __bf16 bf16x8 __attribute__((ext_vector_type(8)));
typedef float f32x4 __attribute__((ext_vector_type(4)));
typedef float f32x16 __attribute__((ext_vector_type(16)));

#define QSCALE 0.18033688011112042f /* 0.125 * log2(e) */

__device__ __forceinline__ u16 f2bf(float f) {
  union { float f; unsigned int u; } v;
  v.f = f;
  unsigned int r = v.u + 0x7fffu + ((v.u >> 16) & 1u);
  return (u16)(r >> 16);
}

__device__ __forceinline__ u32 pack2bf(float lo, float hi) {
  __bf16 a = (__bf16)lo, b = (__bf16)hi;
  return (u32)__builtin_bit_cast(u16, a) | ((u32)__builtin_bit_cast(u16, b) << 16);
}

__device__ __forceinline__ float fexp2(float x) {
#if __has_builtin(__builtin_amdgcn_exp2f)
  return __builtin_amdgcn_exp2f(x);
#else
  return __builtin_exp2f(x);
#endif
}

__device__ __forceinline__ f32x4 mfma16(bf16x8 a, bf16x8 b, f32x4 c) {
  return __builtin_amdgcn_mfma_f32_16x16x32_bf16(a, b, c, 0, 0, 0);
}
__device__ __forceinline__ f32x16 mfma32(bf16x8 a, bf16x8 b, f32x16 c) {
  return __builtin_amdgcn_mfma_f32_32x32x16_bf16(a, b, c, 0, 0, 0);
}

// async global->LDS, 16B per lane; lds base must be wave-uniform.
__device__ __forceinline__ void gl_lds16(const u16* g, u16* l) {
  __builtin_amdgcn_global_load_lds(
      (const __attribute__((address_space(1))) u32*)(const void*)g,
      (__attribute__((address_space(3))) u32*)(void*)l, 16, 0, 0);
}

#define ZERO16 {0.f,0.f,0.f,0.f,0.f,0.f,0.f,0.f,0.f,0.f,0.f,0.f,0.f,0.f,0.f,0.f}

// ---------------------------------------------------------------- prep ----
// Fused: every block casts 1/1024 of x (1024 float4 each) -> bf16, then does
// its weight tile. z: 0..2 -> Wq/Wk/Wv, 3 -> Wo (+bias).
__global__ __launch_bounds__(256) void prep_all(
    const float4* __restrict__ x4, uint2* __restrict__ xb2,
    const float* __restrict__ Wq, const float* __restrict__ Wk,
    const float* __restrict__ Wv, const float* __restrict__ Wo,
    const float* __restrict__ bq, const float* __restrict__ bk,
    const float* __restrict__ bv, const float* __restrict__ bo,
    u16* __restrict__ wT, u16* __restrict__ woT, float* __restrict__ bqkv,
    float* __restrict__ bsum) {
  __shared__ u16 tile[64][72];
  const int tid = threadIdx.x;
  const int z = blockIdx.z;
  const int h = blockIdx.x;
  const int d0 = blockIdx.y * 64;
  {
    int bid = (z * 16 + blockIdx.y) * 16 + blockIdx.x;
    int base = bid * 1024 + tid;
#pragma unroll
    for (int k = 0; k < 4; ++k) {
      int i = base + k * 256;
      float4 v = x4[i];
      xb2[i] = make_uint2(pack2bf(v.x, v.y), pack2bf(v.z, v.w));
    }
  }
  if (z < 3) {
    const float* W = (z == 0) ? Wq : ((z == 1) ? Wk : Wv);
    const float scale = (z == 0) ? QSCALE : 1.0f;
#pragma unroll
    for (int p = 0; p < 16; ++p) {
      int idx = p * 256 + tid;
      int r = idx >> 6, f = idx & 63;
      tile[f][r] = f2bf(W[(size_t)h * 65536 + (size_t)(d0 + r) * 64 + f] * scale);
    }
    __syncthreads();
#pragma unroll
    for (int p = 0; p < 4; ++p) {
      int idx = p * 256 + tid;
      int f = idx >> 4, c4 = (idx & 15) * 4;
      *(uint2*)(wT + (size_t)z * 1048576 + (size_t)(h * 64 + f) * 1024 + d0 + c4) =
          *(const uint2*)&tile[f][c4];
    }
  } else {
#pragma unroll
    for (int p = 0; p < 16; ++p) {
      int idx = p * 256 + tid;
      int r = idx >> 6, cc = idx & 63;
      tile[cc][r] = f2bf(Wo[(size_t)(h * 64 + r) * 1024 + d0 + cc]);
    }
    __syncthreads();
#pragma unroll
    for (int p = 0; p < 4; ++p) {
      int idx = p * 256 + tid;
      int dr = idx >> 4, c4 = (idx & 15) * 4;
      *(uint2*)(woT + (size_t)(d0 + dr) * 1024 + h * 64 + c4) =
          *(const uint2*)&tile[dr][c4];
    }
    if (h == 0 && blockIdx.y == 0) {
      for (int i = tid; i < 1024; i += 256) {
        float s = 0.f;
        for (int hh = 0; hh < 16; ++hh) s += bo[hh * 1024 + i];
        bsum[i] = s;
        bqkv[i] = bq[i] * QSCALE;
        bqkv[1024 + i] = bk[i];
        bqkv[2048 + i] = bv[i];
      }
    }
  }
}

// ------------------------------------------------------------- GEMM core ---
__device__ __forceinline__ void gemm_main(const u16* __restrict__ A,
                                          const u16* __restrict__ B,
                                          f32x4 acc[4][4], u16* la, u16* lb,
                                          int tid) {
  const int lane = tid & 63;
  const int wid = tid >> 6;
  const int lr = lane & 15;
  const int lg = lane >> 4;
  const int wrow = (wid >> 1) << 6;
  const int wcol = (wid & 1) << 6;
  const int swz = lr & 7;
  for (int k0 = 0; k0 < 1024; k0 += 64) {
#pragma unroll
    for (int p = 0; p < 4; ++p) {
      int gs = p * 256 + tid;
      int row = gs >> 3;
      int col = ((tid & 7) ^ (row & 7)) * 8;
      gl_lds16(A + (size_t)row * 1024 + k0 + col, la + (p * 4 + wid) * 512);
      gl_lds16(B + (size_t)row * 1024 + k0 + col, lb + (p * 4 + wid) * 512);
    }
    __syncthreads();
#pragma unroll
    for (int kk = 0; kk < 2; ++kk) {
      const int so = ((kk * 4 + lg) ^ swz) << 3;
      bf16x8 af[4], bfr[4];
#pragma unroll
      for (int i = 0; i < 4; ++i) {
        af[i] = *(const bf16x8*)(la + (wrow + i * 16 + lr) * 64 + so);
        bfr[i] = *(const bf16x8*)(lb + (wcol + i * 16 + lr) * 64 + so);
      }
      __builtin_amdgcn_s_setprio(1);
#pragma unroll
      for (int mi = 0; mi < 4; ++mi)
#pragma unroll
        for (int ni = 0; ni < 4; ++ni)
          acc[mi][ni] = mfma16(af[mi], bfr[ni], acc[mi][ni]);
      __builtin_amdgcn_s_setprio(0);
    }
    __syncthreads();
  }
}

// --------------------------------------------------------------- QKV GEMM --
__global__ __launch_bounds__(256) void qkv_gemm(
    const u16* __restrict__ xb, const u16* __restrict__ wT,
    const float* __restrict__ bqkv, u16* __restrict__ qb, u16* __restrict__ kbb,
    u16* __restrict__ vbb) {
  __shared__ __align__(16) u16 lsh[16384];  // 32 KB: GEMM staging, then tile
  const int tid = threadIdx.x;
  const int mm = blockIdx.z;
  const u16* Abase;
  const u16* Bbase;
  if (mm == 2) {  // V: compute C^T (rows = hf, cols = t)
    Abase = wT + 2u * 1048576 + (size_t)(blockIdx.y * 128) * 1024;
    Bbase = xb + (size_t)(blockIdx.x * 128) * 1024;
  } else {
    Abase = xb + (size_t)(blockIdx.x * 128) * 1024;
    Bbase = wT + (size_t)mm * 1048576 + (size_t)(blockIdx.y * 128) * 1024;
  }
  f32x4 acc[4][4];
#pragma unroll
  for (int mi = 0; mi < 4; ++mi)
#pragma unroll
    for (int ni = 0; ni < 4; ++ni) acc[mi][ni] = (f32x4){0.f, 0.f, 0.f, 0.f};
  gemm_main(Abase, Bbase, acc, lsh, lsh + 8192, tid);
  const int lane = tid & 63, wid = tid >> 6, lr = lane & 15, lg = lane >> 4;
  const int wrow = (wid >> 1) << 6, wcol = (wid & 1) << 6;
  if (mm != 2) {
    // Q and K: rows = t, cols = hf. Stage [t_loc][hf chunks swizzled].
#pragma unroll
    for (int mi = 0; mi < 4; ++mi)
#pragma unroll
      for (int ni = 0; ni < 4; ++ni)
#pragma unroll
        for (int j = 0; j < 4; ++j) {
          int t_loc = wrow + mi * 16 + lg * 4 + j;
          int hf_loc = wcol + ni * 16 + lr;
          float v = acc[mi][ni][j] +
                    bqkv[mm * 1024 + blockIdx.y * 128 + hf_loc];
          int ch = hf_loc >> 3, off = hf_loc & 7;
          lsh[t_loc * 128 + (((ch & 8) | ((ch ^ t_loc) & 7)) << 3) + off] =
              f2bf(v);
        }
    __syncthreads();
    const int t0g = blockIdx.x * 128;
    if (mm == 0) {
#pragma unroll
      for (int p = 0; p < 8; ++p) {
        int o = p * 256 + tid;  // t_loc(7) hh(1) fc(3)
        int fc = o & 7, hh = (o >> 3) & 1, t_loc = o >> 4;
        int ch = hh * 8 + fc;
        uint4 val = *(const uint4*)&lsh[t_loc * 128 +
                                        (((ch & 8) | ((ch ^ t_loc) & 7)) << 3)];
        int t = t0g + t_loc;
        int b = t >> 11, tt = t & 2047;
        size_t bh = (size_t)(b * 16 + blockIdx.y * 2 + hh);
        *(uint4*)&qb[(bh * 2048 + tt) * 64 + fc * 8] = val;
      }
    } else {
#pragma unroll
      for (int p = 0; p < 8; ++p) {
        int o = p * 256 + tid;  // hh(1) dc(3) t_loc(7)
        int t_loc = o & 127, dc = (o >> 7) & 7, hh = o >> 10;
        int ch = hh * 8 + dc;
        uint4 val = *(const uint4*)&lsh[t_loc * 128 +
                                        (((ch & 8) | ((ch ^ t_loc) & 7)) << 3)];
        int t = t0g + t_loc;
        int b = t >> 11, tt = t & 2047;
        size_t bh = (size_t)(b * 16 + blockIdx.y * 2 + hh);
        *(uint4*)&kbb[bh * 131072 + (size_t)(tt >> 6) * 4096 + dc * 512 +
                      (tt & 63) * 8] = val;
      }
    }
  } else {
    // V: rows hf, cols t; stage [hf_loc][t chunks swizzled]
#pragma unroll
    for (int mi = 0; mi < 4; ++mi)
#pragma unroll
      for (int ni = 0; ni < 4; ++ni)
#pragma unroll
        for (int j = 0; j < 4; ++j) {
          int hf_loc = wrow + mi * 16 + lg * 4 + j;
          int t_loc = wcol + ni * 16 + lr;
          float v = acc[mi][ni][j] + bqkv[2048 + blockIdx.y * 128 + hf_loc];
          int tch = t_loc >> 3, off = t_loc & 7;
          lsh[hf_loc * 128 + (((tch & 8) | ((tch ^ hf_loc) & 7)) << 3) + off] =
              f2bf(v);
        }
    __syncthreads();
    const int tcol0 = blockIdx.x * 128;
#pragma unroll
    for (int p = 0; p < 8; ++p) {
      int o = p * 256 + tid;  // hh(1) tb(1) sc(3) f(6)
      int f = o & 63, sc = (o >> 6) & 7, tb = (o >> 9) & 1, hh = o >> 10;
      int hf_loc = hh * 64 + f;
      int tch = tb * 8 + sc;
      uint4 val = *(const uint4*)&lsh[hf_loc * 128 +
                                      (((tch & 8) | ((tch ^ hf_loc) & 7)) << 3)];
      int t = tcol0 + tch * 8;
      int b = t >> 11, tt = t & 2047;
      size_t bh = (size_t)(b * 16 + blockIdx.y * 2 + hh);
      *(uint4*)&vbb[bh * 131072 + (size_t)(tt >> 6) * 4096 +
                    ((tt >> 3) & 7) * 512 + f * 8] = val;
    }
  }
}

// --------------------------------------------------------------- attention -
// 512 threads/block, 512 blocks: block = 128 q-rows x full KV, one bh.
// 8 waves: wq = wid&3 (32-q-row tile), kvhalf = wid>>2 (16 KV tiles each).
// Each 4-wave half stages its KV tiles into its own linear LDS double-buffer
// (R18-proven dedup: 4 waves share each staged tile). 2 blocks/CU x 8 waves
// = 4 waves/SIMD at the deduped L2 traffic. Exact-add combine of the two
// halves (fixed-reference softmax) via LDS overlay, then R13-proven epilogue.
#define PV_GROUP(A0, A1, B0, B1, VF0, VF1)                                    \
  {                                                                           \
    u32 xa = (A0), xb_ = (B0), ya = (A1), yb = (B1);                          \
    asm("v_permlane32_swap_b32 %0, %1" : "+v"(xa), "+v"(xb_));                \
    asm("v_permlane32_swap_b32 %0, %1" : "+v"(ya), "+v"(yb));                 \
    uint4 wv = make_uint4(xa, ya, xb_, yb);                                   \
    bf16x8 pf = __builtin_bit_cast(bf16x8, wv);                               \
    acc0 = mfma32((VF0), pf, acc0);                                           \
    acc1 = mfma32((VF1), pf, acc1);                                           \
  }

__global__ __launch_bounds__(512, 2) void attn_kernel(
    const u16* __restrict__ qb, const u16* __restrict__ kbb,
    const u16* __restrict__ vbb, u16* __restrict__ ctx) {
  __shared__ __align__(16) u16 kv[2][2][8192];  // [kvhalf][buf] 16KB tiles
  const int tid = threadIdx.x;
  const int lane = tid & 63;
  const int wid = tid >> 6;     // 0..7
  const int wq = wid & 3;       // q-tile
  const int kvhalf = wid >> 2;  // s-half
  const int c = lane & 31;
  const int hi = lane >> 5;
  const int lin = blockIdx.y * 16 + blockIdx.x;  // 0..511
  const int xcd = lin & 7;
  const int rest = lin >> 3;  // 0..63: 4 bh x 16 q-slots per XCD
  const int bh = xcd * 4 + (rest >> 4);
  const int q0w = (rest & 15) * 128 + wq * 32;

  bf16x8 qf[4];
#pragma unroll
  for (int kki = 0; kki < 4; ++kki)
    qf[kki] = *(const bf16x8*)(qb + ((size_t)(bh * 2048 + q0w + c)) * 64 +
                               kki * 16 + hi * 8);

  const u16* kb_ = kbb + (size_t)bh * 131072;
  const u16* vb_ = vbb + (size_t)bh * 131072;

  f32x16 acc0 = ZERO16, acc1 = ZERO16;
  float lsum = 0.f;
  const int it0 = kvhalf * 16;

  // stage tile IT into this half's buffer BUF (4 waves cooperate, linear)
#define STAGE(BUF, IT)                                                        \
  {                                                                           \
    const u16* bk = kb_ + (IT) * 4096;                                        \
    const u16* bv = vb_ + (IT) * 4096;                                        \
    _Pragma("unroll") for (int p = 0; p < 2; ++p) {                           \
      int ch = (p * 4 + wq) * 64 + lane;                                      \
      gl_lds16(bk + ch * 8, &kv[kvhalf][BUF][(p * 4 + wq) * 512]);            \
      gl_lds16(bv + ch * 8, &kv[kvhalf][BUF][4096 + (p * 4 + wq) * 512]);     \
    }                                                                         \
  }

  STAGE(0, it0)
  __syncthreads();

  for (int j = 0; j < 16; ++j) {
    const int cur = j & 1;
    if (j < 15) STAGE(cur ^ 1, it0 + j + 1)
    const u16* kbuf = &kv[kvhalf][cur][0];
    const u16* vbuf = &kv[kvhalf][cur][4096];
    bf16x8 kA[4], kB[4], vA[4], vB[4];
#pragma unroll
    for (int kki = 0; kki < 4; ++kki) {
      kA[kki] = *(const bf16x8*)(kbuf + (kki * 2 + hi) * 512 + c * 8);
      kB[kki] = *(const bf16x8*)(kbuf + (kki * 2 + hi) * 512 + 256 + c * 8);
    }
#pragma unroll
    for (int g = 0; g < 4; ++g) {
      vA[g] = *(const bf16x8*)(vbuf + (g * 2 + hi) * 512 + c * 8);
      vB[g] = *(const bf16x8*)(vbuf + (g * 2 + hi) * 512 + 256 + c * 8);
    }
    f32x16 sA = ZERO16, sB = ZERO16;
    __builtin_amdgcn_s_setprio(1);
#pragma unroll
    for (int kki = 0; kki < 4; ++kki) {
      sA = mfma32(kA[kki], qf[kki], sA);
      sB = mfma32(kB[kki], qf[kki], sB);
    }
    __builtin_amdgcn_s_setprio(0);
    float a0 = fexp2(sA[0]), a1 = fexp2(sA[1]);
    float a2 = fexp2(sA[2]), a3 = fexp2(sA[3]);
    float a4 = fexp2(sA[4]), a5 = fexp2(sA[5]);
    float a6 = fexp2(sA[6]), a7 = fexp2(sA[7]);
    float a8 = fexp2(sA[8]), a9 = fexp2(sA[9]);
    float a10 = fexp2(sA[10]), a11 = fexp2(sA[11]);
    float a12 = fexp2(sA[12]), a13 = fexp2(sA[13]);
    float a14 = fexp2(sA[14]), a15 = fexp2(sA[15]);
    float b0 = fexp2(sB[0]), b1 = fexp2(sB[1]);
    float b2 = fexp2(sB[2]), b3 = fexp2(sB[3]);
    float b4 = fexp2(sB[4]), b5 = fexp2(sB[5]);
    float b6 = fexp2(sB[6]), b7 = fexp2(sB[7]);
    float b8 = fexp2(sB[8]), b9 = fexp2(sB[9]);
    float b10 = fexp2(sB[10]), b11 = fexp2(sB[11]);
    float b12 = fexp2(sB[12]), b13 = fexp2(sB[13]);
    float b14 = fexp2(sB[14]), b15 = fexp2(sB[15]);
    float sa = (((a0 + a1) + (a2 + a3)) + ((a4 + a5) + (a6 + a7))) +
               (((a8 + a9) + (a10 + a11)) + ((a12 + a13) + (a14 + a15)));
    float sb = (((b0 + b1) + (b2 + b3)) + ((b4 + b5) + (b6 + b7))) +
               (((b8 + b9) + (b10 + b11)) + ((b12 + b13) + (b14 + b15)));
    lsum += sa + sb;
    u32 pkA00 = pack2bf(a0, a1), pkA01 = pack2bf(a2, a3);
    u32 pkA10 = pack2bf(a4, a5), pkA11 = pack2bf(a6, a7);
    u32 pkA20 = pack2bf(a8, a9), pkA21 = pack2bf(a10, a11);
    u32 pkA30 = pack2bf(a12, a13), pkA31 = pack2bf(a14, a15);
    u32 pkB00 = pack2bf(b0, b1), pkB01 = pack2bf(b2, b3);
    u32 pkB10 = pack2bf(b4, b5), pkB11 = pack2bf(b6, b7);
    u32 pkB20 = pack2bf(b8, b9), pkB21 = pack2bf(b10, b11);
    u32 pkB30 = pack2bf(b12, b13), pkB31 = pack2bf(b14, b15);
    __builtin_amdgcn_s_setprio(1);
    PV_GROUP(pkA00, pkA01, pkA10, pkA11, vA[0], vB[0])
    PV_GROUP(pkA20, pkA21, pkA30, pkA31, vA[1], vB[1])
    PV_GROUP(pkB00, pkB01, pkB10, pkB11, vA[2], vB[2])
    PV_GROUP(pkB20, pkB21, pkB30, pkB31, vA[3], vB[3])
    __builtin_amdgcn_s_setprio(0);
    __syncthreads();
  }
  // complete the row sum across the hi-halves of this wave
  lsum += __shfl_xor(lsum, 32, 64);

  // ---- combine the two kv-halves: exact add (fixed reference), LDS overlay
  float* cacc = (float*)&kv[0][0][0];             // [wq][2048] f32 = 32 KB
  float* cl = (float*)&kv[1][0][0];               // [wq][64]  f32 = 1 KB
  u16* scr = (u16*)&kv[1][0][0] + 2048 + wq * 2048;  // 4 x 4 KB
  // (loop's final __syncthreads ensures all waves are done with kv data)
  if (kvhalf) {
#pragma unroll
    for (int k = 0; k < 8; ++k) {
      f32x4 v4;
      if (k < 4)
        v4 = (f32x4){acc0[4 * k], acc0[4 * k + 1], acc0[4 * k + 2],
                     acc0[4 * k + 3]};
      else
        v4 = (f32x4){acc1[4 * (k - 4)], acc1[4 * (k - 4) + 1],
                     acc1[4 * (k - 4) + 2], acc1[4 * (k - 4) + 3]};
      *(f32x4*)&cacc[wq * 2048 + lane * 32 + ((k ^ (lane & 7)) << 2)] = v4;
    }
    cl[wq * 64 + lane] = lsum;
  }
  __syncthreads();
  if (kvhalf) return;
#pragma unroll
  for (int k = 0; k < 8; ++k) {
    f32x4 v4 =
        *(const f32x4*)&cacc[wq * 2048 + lane * 32 + ((k ^ (lane & 7)) << 2)];
    if (k < 4) {
#pragma unroll
      for (int ii = 0; ii < 4; ++ii) acc0[4 * k + ii] += v4[ii];
    } else {
#pragma unroll
      for (int ii = 0; ii < 4; ++ii) acc1[4 * (k - 4) + ii] += v4[ii];
    }
  }
  float l = lsum + cl[wq * 64 + lane];
  float invl = 1.0f / l;

  // ---- epilogue: normalize, transpose ctx^T -> ctx via per-wq LDS scratch
#pragma unroll
  for (int g = 0; g < 8; ++g) {
    int f0 = 2 * (g & 1) + 8 * (g >> 1) + 4 * hi;
    *(u32*)(scr + (((c * 64 + f0) ^ ((c & 7) << 3)))) =
        pack2bf(acc0[2 * g] * invl, acc0[2 * g + 1] * invl);
    *(u32*)(scr + (((c * 64 + f0 + 32) ^ ((c & 7) << 3)))) =
        pack2bf(acc1[2 * g] * invl, acc1[2 * g + 1] * invl);
  }
  const int b = bh >> 4, h = bh & 15;
#pragma unroll
  for (int pass = 0; pass < 4; ++pass) {
    int trow = pass * 8 + (lane >> 3);
    int chunk = lane & 7;
    uint4 val =
        *(const uint4*)(scr + ((trow * 64 + chunk * 8) ^ ((trow & 7) << 3)));
    *(uint4*)(ctx + ((size_t)(b * 2048 + q0w + trow)) * 1024 + h * 64 +
              chunk * 8) = val;
  }
}

// ---------------------------------------------------------------- out GEMM -
__global__ __launch_bounds__(256) void out_gemm(const u16* __restrict__ ctx,
                                                const u16* __restrict__ woT,
                                                const float* __restrict__ bsum,
                                                float* __restrict__ out) {
  __shared__ __align__(16) u16 la[8192];
  __shared__ __align__(16) u16 lb[8192];
  const int tid = threadIdx.x;
  const int rt0 = blockIdx.x * 128;
  const int c0 = blockIdx.y * 128;
  f32x4 acc[4][4];
#pragma unroll
  for (int mi = 0; mi < 4; ++mi)
#pragma unroll
    for (int ni = 0; ni < 4; ++ni) acc[mi][ni] = (f32x4){0.f, 0.f, 0.f, 0.f};
  gemm_main(ctx + (size_t)rt0 * 1024, woT + (size_t)c0 * 1024, acc, la, lb,
            tid);
  const int lane = tid & 63, wid = tid >> 6, lr = lane & 15, lg = lane >> 4;
  const int wrow = (wid >> 1) << 6, wcol = (wid & 1) << 6;
#pragma unroll
  for (int mi = 0; mi < 4; ++mi)
#pragma unroll
    for (int ni = 0; ni < 4; ++ni)
#pragma unroll
      for (int j = 0; j < 4; ++j) {
        int rt = rt0 + wrow + mi * 16 + lg * 4 + j;
        int d = c0 + wcol + ni * 16 + lr;
        out[(size_t)rt * 1024 + d] = acc[mi][ni][j] + bsum[d];
      }
}

// ------------------------------------------------------------------ launch -
extern "C" void kernel_launch(void* const* d_in, const int* in_sizes, int n_in,
                              void* d_out, int out_size, void* d_ws,
                              size_t ws_size, hipStream_t stream) {
  (void)in_sizes; (void)n_in; (void)out_size; (void)ws_size;
  const float* x  = (const float*)d_in[0];
  const float* Wq = (const float*)d_in[2];
  const float* Wk = (const float*)d_in[3];
  const float* Wv = (const float*)d_in[4];
  const float* Wo = (const float*)d_in[5];
  const float* bq = (const float*)d_in[6];
  const float* bk = (const float*)d_in[7];
  const float* bv = (const float*)d_in[8];
  const float* bo = (const float*)d_in[9];

  char* w = (char*)d_ws;
  u16* xb  = (u16*)(w);                     // 8 MB (reused as ctx)
  u16* ctx = (u16*)(w);
  u16* qb  = (u16*)(w + (8ull << 20));      // 8 MB (Q pre-scaled by 0.125*log2e)
  u16* kbb = (u16*)(w + (16ull << 20));     // 8 MB  K blocked
  u16* vbb = (u16*)(w + (24ull << 20));     // 8 MB  V blocked
  u16* wT  = (u16*)(w + (32ull << 20));     // 6 MB  [3][hf][d]
  u16* woT = (u16*)(w + (38ull << 20));     // 2 MB  [d][hf]
  float* bqkv = (float*)(w + (40ull << 20));
  float* bsum = (float*)(w + (40ull << 20) + (12u << 10));
  float* out = (float*)d_out;

  prep_all<<<dim3(16, 16, 4), 256, 0, stream>>>(
      (const float4*)x, (uint2*)xb, Wq, Wk, Wv, Wo, bq, bk, bv, bo, wT, woT,
      bqkv, bsum);
  qkv_gemm<<<dim3(32, 8, 3), 256, 0, stream>>>(xb, wT, bqkv, qb, kbb, vbb);
  attn_kernel<<<dim3(16, 32), 512, 0, stream>>>(qb, kbb, vbb, ctx);
  out_gemm<<<dim3(32, 8), 256, 0, stream>>>(ctx, woT, bsum, out);
}

// Round 20
// 122.947 us; speedup vs baseline: 1.0016x; 1.0016x over previous
//
#include <hip/hip_runtime.h>

typedef unsigned short u16;
typedef unsigned int u32;
typedef __bf16 bf16x8 __attribute__((ext_vector_type(8)));
typedef float f32x4 __attribute__((ext_vector_type(4)));
typedef float f32x16 __attribute__((ext_vector_type(16)));

#define QSCALE 0.18033688011112042f /* 0.125 * log2(e) */

__device__ __forceinline__ u16 f2bf(float f) {
  union { float f; unsigned int u; } v;
  v.f = f;
  unsigned int r = v.u + 0x7fffu + ((v.u >> 16) & 1u);
  return (u16)(r >> 16);
}

__device__ __forceinline__ u32 pack2bf(float lo, float hi) {
  __bf16 a = (__bf16)lo, b = (__bf16)hi;
  return (u32)__builtin_bit_cast(u16, a) | ((u32)__builtin_bit_cast(u16, b) << 16);
}

__device__ __forceinline__ float fexp2(float x) {
#if __has_builtin(__builtin_amdgcn_exp2f)
  return __builtin_amdgcn_exp2f(x);
#else
  return __builtin_exp2f(x);
#endif
}

__device__ __forceinline__ f32x4 mfma16(bf16x8 a, bf16x8 b, f32x4 c) {
  return __builtin_amdgcn_mfma_f32_16x16x32_bf16(a, b, c, 0, 0, 0);
}
__device__ __forceinline__ f32x16 mfma32(bf16x8 a, bf16x8 b, f32x16 c) {
  return __builtin_amdgcn_mfma_f32_32x32x16_bf16(a, b, c, 0, 0, 0);
}

// async global->LDS, 16B per lane; lds base must be wave-uniform.
__device__ __forceinline__ void gl_lds16(const u16* g, u16* l) {
  __builtin_amdgcn_global_load_lds(
      (const __attribute__((address_space(1))) u32*)(const void*)g,
      (__attribute__((address_space(3))) u32*)(void*)l, 16, 0, 0);
}

#define ZERO16 {0.f,0.f,0.f,0.f,0.f,0.f,0.f,0.f,0.f,0.f,0.f,0.f,0.f,0.f,0.f,0.f}

// ---------------------------------------------------------------- prep ----
// Fused: every block casts 1/1024 of x (1024 float4 each) -> bf16, then does
// its weight tile. z: 0..2 -> Wq/Wk/Wv, 3 -> Wo (+bias).
__global__ __launch_bounds__(256) void prep_all(
    const float4* __restrict__ x4, uint2* __restrict__ xb2,
    const float* __restrict__ Wq, const float* __restrict__ Wk,
    const float* __restrict__ Wv, const float* __restrict__ Wo,
    const float* __restrict__ bq, const float* __restrict__ bk,
    const float* __restrict__ bv, const float* __restrict__ bo,
    u16* __restrict__ wT, u16* __restrict__ woT, float* __restrict__ bqkv,
    float* __restrict__ bsum) {
  __shared__ u16 tile[64][72];
  const int tid = threadIdx.x;
  const int z = blockIdx.z;
  const int h = blockIdx.x;
  const int d0 = blockIdx.y * 64;
  {
    int bid = (z * 16 + blockIdx.y) * 16 + blockIdx.x;
    int base = bid * 1024 + tid;
#pragma unroll
    for (int k = 0; k < 4; ++k) {
      int i = base + k * 256;
      float4 v = x4[i];
      xb2[i] = make_uint2(pack2bf(v.x, v.y), pack2bf(v.z, v.w));
    }
  }
  if (z < 3) {
    const float* W = (z == 0) ? Wq : ((z == 1) ? Wk : Wv);
    const float scale = (z == 0) ? QSCALE : 1.0f;
#pragma unroll
    for (int p = 0; p < 16; ++p) {
      int idx = p * 256 + tid;
      int r = idx >> 6, f = idx & 63;
      tile[f][r] = f2bf(W[(size_t)h * 65536 + (size_t)(d0 + r) * 64 + f] * scale);
    }
    __syncthreads();
#pragma unroll
    for (int p = 0; p < 4; ++p) {
      int idx = p * 256 + tid;
      int f = idx >> 4, c4 = (idx & 15) * 4;
      *(uint2*)(wT + (size_t)z * 1048576 + (size_t)(h * 64 + f) * 1024 + d0 + c4) =
          *(const uint2*)&tile[f][c4];
    }
  } else {
#pragma unroll
    for (int p = 0; p < 16; ++p) {
      int idx = p * 256 + tid;
      int r = idx >> 6, cc = idx & 63;
      tile[cc][r] = f2bf(Wo[(size_t)(h * 64 + r) * 1024 + d0 + cc]);
    }
    __syncthreads();
#pragma unroll
    for (int p = 0; p < 4; ++p) {
      int idx = p * 256 + tid;
      int dr = idx >> 4, c4 = (idx & 15) * 4;
      *(uint2*)(woT + (size_t)(d0 + dr) * 1024 + h * 64 + c4) =
          *(const uint2*)&tile[dr][c4];
    }
    if (h == 0 && blockIdx.y == 0) {
      for (int i = tid; i < 1024; i += 256) {
        float s = 0.f;
        for (int hh = 0; hh < 16; ++hh) s += bo[hh * 1024 + i];
        bsum[i] = s;
        bqkv[i] = bq[i] * QSCALE;
        bqkv[1024 + i] = bk[i];
        bqkv[2048 + i] = bv[i];
      }
    }
  }
}

// ------------------------------------------------------------- GEMM core ---
__device__ __forceinline__ void gemm_main(const u16* __restrict__ A,
                                          const u16* __restrict__ B,
                                          f32x4 acc[4][4], u16* la, u16* lb,
                                          int tid) {
  const int lane = tid & 63;
  const int wid = tid >> 6;
  const int lr = lane & 15;
  const int lg = lane >> 4;
  const int wrow = (wid >> 1) << 6;
  const int wcol = (wid & 1) << 6;
  const int swz = lr & 7;
  for (int k0 = 0; k0 < 1024; k0 += 64) {
#pragma unroll
    for (int p = 0; p < 4; ++p) {
      int gs = p * 256 + tid;
      int row = gs >> 3;
      int col = ((tid & 7) ^ (row & 7)) * 8;
      gl_lds16(A + (size_t)row * 1024 + k0 + col, la + (p * 4 + wid) * 512);
      gl_lds16(B + (size_t)row * 1024 + k0 + col, lb + (p * 4 + wid) * 512);
    }
    __syncthreads();
#pragma unroll
    for (int kk = 0; kk < 2; ++kk) {
      const int so = ((kk * 4 + lg) ^ swz) << 3;
      bf16x8 af[4], bfr[4];
#pragma unroll
      for (int i = 0; i < 4; ++i) {
        af[i] = *(const bf16x8*)(la + (wrow + i * 16 + lr) * 64 + so);
        bfr[i] = *(const bf16x8*)(lb + (wcol + i * 16 + lr) * 64 + so);
      }
      __builtin_amdgcn_s_setprio(1);
#pragma unroll
      for (int mi = 0; mi < 4; ++mi)
#pragma unroll
        for (int ni = 0; ni < 4; ++ni)
          acc[mi][ni] = mfma16(af[mi], bfr[ni], acc[mi][ni]);
      __builtin_amdgcn_s_setprio(0);
    }
    __syncthreads();
  }
}

// --------------------------------------------------------------- QKV GEMM --
// XCD-aware swizzle (T1): each XCD owns 4 contiguous row-tiles x all 8
// col-tiles -> x-row panels are XCD-L2-resident, reused across col-tiles
// and across the 3 z-matrices.
__global__ __launch_bounds__(256) void qkv_gemm(
    const u16* __restrict__ xb, const u16* __restrict__ wT,
    const float* __restrict__ bqkv, u16* __restrict__ qb, u16* __restrict__ kbb,
    u16* __restrict__ vbb) {
  __shared__ __align__(16) u16 lsh[16384];  // 32 KB: GEMM staging, then tile
  const int tid = threadIdx.x;
  const int mm = blockIdx.z;
  const int lin = blockIdx.y * 32 + blockIdx.x;  // 0..255
  const int xcd = lin & 7;
  const int s = lin >> 3;            // 0..31
  const int bx = xcd * 4 + (s & 3);  // row-tile 0..31
  const int by = s >> 2;             // col-tile 0..7
  const u16* Abase;
  const u16* Bbase;
  if (mm == 2) {  // V: compute C^T (rows = hf, cols = t)
    Abase = wT + 2u * 1048576 + (size_t)(by * 128) * 1024;
    Bbase = xb + (size_t)(bx * 128) * 1024;
  } else {
    Abase = xb + (size_t)(bx * 128) * 1024;
    Bbase = wT + (size_t)mm * 1048576 + (size_t)(by * 128) * 1024;
  }
  f32x4 acc[4][4];
#pragma unroll
  for (int mi = 0; mi < 4; ++mi)
#pragma unroll
    for (int ni = 0; ni < 4; ++ni) acc[mi][ni] = (f32x4){0.f, 0.f, 0.f, 0.f};
  gemm_main(Abase, Bbase, acc, lsh, lsh + 8192, tid);
  const int lane = tid & 63, wid = tid >> 6, lr = lane & 15, lg = lane >> 4;
  const int wrow = (wid >> 1) << 6, wcol = (wid & 1) << 6;
  if (mm != 2) {
    // Q and K: rows = t, cols = hf. Stage [t_loc][hf chunks swizzled].
#pragma unroll
    for (int mi = 0; mi < 4; ++mi)
#pragma unroll
      for (int ni = 0; ni < 4; ++ni)
#pragma unroll
        for (int j = 0; j < 4; ++j) {
          int t_loc = wrow + mi * 16 + lg * 4 + j;
          int hf_loc = wcol + ni * 16 + lr;
          float v = acc[mi][ni][j] + bqkv[mm * 1024 + by * 128 + hf_loc];
          int ch = hf_loc >> 3, off = hf_loc & 7;
          lsh[t_loc * 128 + (((ch & 8) | ((ch ^ t_loc) & 7)) << 3) + off] =
              f2bf(v);
        }
    __syncthreads();
    const int t0g = bx * 128;
    if (mm == 0) {
#pragma unroll
      for (int p = 0; p < 8; ++p) {
        int o = p * 256 + tid;  // t_loc(7) hh(1) fc(3)
        int fc = o & 7, hh = (o >> 3) & 1, t_loc = o >> 4;
        int ch = hh * 8 + fc;
        uint4 val = *(const uint4*)&lsh[t_loc * 128 +
                                        (((ch & 8) | ((ch ^ t_loc) & 7)) << 3)];
        int t = t0g + t_loc;
        int b = t >> 11, tt = t & 2047;
        size_t bh = (size_t)(b * 16 + by * 2 + hh);
        *(uint4*)&qb[(bh * 2048 + tt) * 64 + fc * 8] = val;
      }
    } else {
#pragma unroll
      for (int p = 0; p < 8; ++p) {
        int o = p * 256 + tid;  // hh(1) dc(3) t_loc(7)
        int t_loc = o & 127, dc = (o >> 7) & 7, hh = o >> 10;
        int ch = hh * 8 + dc;
        uint4 val = *(const uint4*)&lsh[t_loc * 128 +
                                        (((ch & 8) | ((ch ^ t_loc) & 7)) << 3)];
        int t = t0g + t_loc;
        int b = t >> 11, tt = t & 2047;
        size_t bh = (size_t)(b * 16 + by * 2 + hh);
        *(uint4*)&kbb[bh * 131072 + (size_t)(tt >> 6) * 4096 + dc * 512 +
                      (tt & 63) * 8] = val;
      }
    }
  } else {
    // V: rows hf, cols t; stage [hf_loc][t chunks swizzled]
#pragma unroll
    for (int mi = 0; mi < 4; ++mi)
#pragma unroll
      for (int ni = 0; ni < 4; ++ni)
#pragma unroll
        for (int j = 0; j < 4; ++j) {
          int hf_loc = wrow + mi * 16 + lg * 4 + j;
          int t_loc = wcol + ni * 16 + lr;
          float v = acc[mi][ni][j] + bqkv[2048 + by * 128 + hf_loc];
          int tch = t_loc >> 3, off = t_loc & 7;
          lsh[hf_loc * 128 + (((tch & 8) | ((tch ^ hf_loc) & 7)) << 3) + off] =
              f2bf(v);
        }
    __syncthreads();
    const int tcol0 = bx * 128;
#pragma unroll
    for (int p = 0; p < 8; ++p) {
      int o = p * 256 + tid;  // hh(1) tb(1) sc(3) f(6)
      int f = o & 63, sc = (o >> 6) & 7, tb = (o >> 9) & 1, hh = o >> 10;
      int hf_loc = hh * 64 + f;
      int tch = tb * 8 + sc;
      uint4 val = *(const uint4*)&lsh[hf_loc * 128 +
                                      (((tch & 8) | ((tch ^ hf_loc) & 7)) << 3)];
      int t = tcol0 + tch * 8;
      int b = t >> 11, tt = t & 2047;
      size_t bh = (size_t)(b * 16 + by * 2 + hh);
      *(uint4*)&vbb[bh * 131072 + (size_t)(tt >> 6) * 4096 +
                    ((tt >> 3) & 7) * 512 + f * 8] = val;
    }
  }
}

// --------------------------------------------------------------- attention -
// R18-proven: 256 threads/block, 512 blocks: block = 128 q-rows x full KV.
// Each wave (wq = wid) owns 32 q-rows, all 32 KV tiles. K/V staged once per
// iter into a linear LDS double-buffer (4-way dedup -> 4x less L2 traffic).
// exp2-direct softmax, VALU lsum + post shfl, permlane32_swap PV exchange.
#define PV_GROUP(A0, A1, B0, B1, VF0, VF1)                                    \
  {                                                                           \
    u32 xa = (A0), xb_ = (B0), ya = (A1), yb = (B1);                          \
    asm("v_permlane32_swap_b32 %0, %1" : "+v"(xa), "+v"(xb_));                \
    asm("v_permlane32_swap_b32 %0, %1" : "+v"(ya), "+v"(yb));                 \
    uint4 wv = make_uint4(xa, ya, xb_, yb);                                   \
    bf16x8 pf = __builtin_bit_cast(bf16x8, wv);                               \
    acc0 = mfma32((VF0), pf, acc0);                                           \
    acc1 = mfma32((VF1), pf, acc1);                                           \
  }

__global__ __launch_bounds__(256, 2) void attn_kernel(
    const u16* __restrict__ qb, const u16* __restrict__ kbb,
    const u16* __restrict__ vbb, u16* __restrict__ ctx) {
  __shared__ __align__(16) u16 kv[2][8192];  // 2 bufs x (K 8KB | V 8KB)
  const int tid = threadIdx.x;
  const int lane = tid & 63;
  const int wid = tid >> 6;  // = wq (0..3)
  const int c = lane & 31;
  const int hi = lane >> 5;
  const int lin = blockIdx.y * 16 + blockIdx.x;  // 0..511
  const int xcd = lin & 7;
  const int rest = lin >> 3;  // 0..63: 4 bh x 16 q-slots per XCD
  const int bh = xcd * 4 + (rest >> 4);
  const int q0w = (rest & 15) * 128 + wid * 32;

  bf16x8 qf[4];
#pragma unroll
  for (int kki = 0; kki < 4; ++kki)
    qf[kki] = *(const bf16x8*)(qb + ((size_t)(bh * 2048 + q0w + c)) * 64 +
                               kki * 16 + hi * 8);

  const u16* kb_ = kbb + (size_t)bh * 131072;
  const u16* vb_ = vbb + (size_t)bh * 131072;

  f32x16 acc0 = ZERO16, acc1 = ZERO16;
  float lsum = 0.f;

#define STAGE(BUF, IT)                                                        \
  {                                                                           \
    const u16* bk = kb_ + (IT) * 4096;                                        \
    const u16* bv = vb_ + (IT) * 4096;                                        \
    _Pragma("unroll") for (int p = 0; p < 2; ++p) {                           \
      int ch = (p * 4 + wid) * 64 + lane;                                     \
      gl_lds16(bk + ch * 8, &kv[BUF][(p * 4 + wid) * 512]);                   \
      gl_lds16(bv + ch * 8, &kv[BUF][4096 + (p * 4 + wid) * 512]);            \
    }                                                                         \
  }

  STAGE(0, 0)
  __syncthreads();

  for (int it = 0; it < 32; ++it) {
    const int cur = it & 1;
    if (it < 31) STAGE(cur ^ 1, it + 1)
    const u16* kbuf = &kv[cur][0];
    const u16* vbuf = &kv[cur][4096];
    bf16x8 kA[4], kB[4], vA[4], vB[4];
#pragma unroll
    for (int kki = 0; kki < 4; ++kki) {
      kA[kki] = *(const bf16x8*)(kbuf + (kki * 2 + hi) * 512 + c * 8);
      kB[kki] = *(const bf16x8*)(kbuf + (kki * 2 + hi) * 512 + 256 + c * 8);
    }
#pragma unroll
    for (int g = 0; g < 4; ++g) {
      vA[g] = *(const bf16x8*)(vbuf + (g * 2 + hi) * 512 + c * 8);
      vB[g] = *(const bf16x8*)(vbuf + (g * 2 + hi) * 512 + 256 + c * 8);
    }
    f32x16 sA = ZERO16, sB = ZERO16;
    __builtin_amdgcn_s_setprio(1);
#pragma unroll
    for (int kki = 0; kki < 4; ++kki) {
      sA = mfma32(kA[kki], qf[kki], sA);
      sB = mfma32(kB[kki], qf[kki], sB);
    }
    __builtin_amdgcn_s_setprio(0);
    float a0 = fexp2(sA[0]), a1 = fexp2(sA[1]);
    float a2 = fexp2(sA[2]), a3 = fexp2(sA[3]);
    float a4 = fexp2(sA[4]), a5 = fexp2(sA[5]);
    float a6 = fexp2(sA[6]), a7 = fexp2(sA[7]);
    float a8 = fexp2(sA[8]), a9 = fexp2(sA[9]);
    float a10 = fexp2(sA[10]), a11 = fexp2(sA[11]);
    float a12 = fexp2(sA[12]), a13 = fexp2(sA[13]);
    float a14 = fexp2(sA[14]), a15 = fexp2(sA[15]);
    float b0 = fexp2(sB[0]), b1 = fexp2(sB[1]);
    float b2 = fexp2(sB[2]), b3 = fexp2(sB[3]);
    float b4 = fexp2(sB[4]), b5 = fexp2(sB[5]);
    float b6 = fexp2(sB[6]), b7 = fexp2(sB[7]);
    float b8 = fexp2(sB[8]), b9 = fexp2(sB[9]);
    float b10 = fexp2(sB[10]), b11 = fexp2(sB[11]);
    float b12 = fexp2(sB[12]), b13 = fexp2(sB[13]);
    float b14 = fexp2(sB[14]), b15 = fexp2(sB[15]);
    float sa = (((a0 + a1) + (a2 + a3)) + ((a4 + a5) + (a6 + a7))) +
               (((a8 + a9) + (a10 + a11)) + ((a12 + a13) + (a14 + a15)));
    float sb = (((b0 + b1) + (b2 + b3)) + ((b4 + b5) + (b6 + b7))) +
               (((b8 + b9) + (b10 + b11)) + ((b12 + b13) + (b14 + b15)));
    lsum += sa + sb;
    u32 pkA00 = pack2bf(a0, a1), pkA01 = pack2bf(a2, a3);
    u32 pkA10 = pack2bf(a4, a5), pkA11 = pack2bf(a6, a7);
    u32 pkA20 = pack2bf(a8, a9), pkA21 = pack2bf(a10, a11);
    u32 pkA30 = pack2bf(a12, a13), pkA31 = pack2bf(a14, a15);
    u32 pkB00 = pack2bf(b0, b1), pkB01 = pack2bf(b2, b3);
    u32 pkB10 = pack2bf(b4, b5), pkB11 = pack2bf(b6, b7);
    u32 pkB20 = pack2bf(b8, b9), pkB21 = pack2bf(b10, b11);
    u32 pkB30 = pack2bf(b12, b13), pkB31 = pack2bf(b14, b15);
    __builtin_amdgcn_s_setprio(1);
    PV_GROUP(pkA00, pkA01, pkA10, pkA11, vA[0], vB[0])
    PV_GROUP(pkA20, pkA21, pkA30, pkA31, vA[1], vB[1])
    PV_GROUP(pkB00, pkB01, pkB10, pkB11, vA[2], vB[2])
    PV_GROUP(pkB20, pkB21, pkB30, pkB31, vA[3], vB[3])
    __builtin_amdgcn_s_setprio(0);
    __syncthreads();
  }
  lsum += __shfl_xor(lsum, 32, 64);
  float invl = 1.0f / lsum;

  // ---- epilogue: normalize, transpose ctx^T -> ctx via per-wave LDS scratch
  u16* scr = &kv[0][0] + wid * 2048;
#pragma unroll
  for (int g = 0; g < 8; ++g) {
    int f0 = 2 * (g & 1) + 8 * (g >> 1) + 4 * hi;
    *(u32*)(scr + (((c * 64 + f0) ^ ((c & 7) << 3)))) =
        pack2bf(acc0[2 * g] * invl, acc0[2 * g + 1] * invl);
    *(u32*)(scr + (((c * 64 + f0 + 32) ^ ((c & 7) << 3)))) =
        pack2bf(acc1[2 * g] * invl, acc1[2 * g + 1] * invl);
  }
  const int b = bh >> 4, h = bh & 15;
#pragma unroll
  for (int pass = 0; pass < 4; ++pass) {
    int trow = pass * 8 + (lane >> 3);
    int chunk = lane & 7;
    uint4 val =
        *(const uint4*)(scr + ((trow * 64 + chunk * 8) ^ ((trow & 7) << 3)));
    *(uint4*)(ctx + ((size_t)(b * 2048 + q0w + trow)) * 1024 + h * 64 +
              chunk * 8) = val;
  }
}

// ---------------------------------------------------------------- out GEMM -
__global__ __launch_bounds__(256) void out_gemm(const u16* __restrict__ ctx,
                                                const u16* __restrict__ woT,
                                                const float* __restrict__ bsum,
                                                float* __restrict__ out) {
  __shared__ __align__(16) u16 la[8192];
  __shared__ __align__(16) u16 lb[8192];
  const int tid = threadIdx.x;
  const int lin = blockIdx.y * 32 + blockIdx.x;  // 0..255
  const int xcd = lin & 7;
  const int s = lin >> 3;
  const int bx = xcd * 4 + (s & 3);
  const int by = s >> 2;
  const int rt0 = bx * 128;
  const int c0 = by * 128;
  f32x4 acc[4][4];
#pragma unroll
  for (int mi = 0; mi < 4; ++mi)
#pragma unroll
    for (int ni = 0; ni < 4; ++ni) acc[mi][ni] = (f32x4){0.f, 0.f, 0.f, 0.f};
  gemm_main(ctx + (size_t)rt0 * 1024, woT + (size_t)c0 * 1024, acc, la, lb,
            tid);
  const int lane = tid & 63, wid = tid >> 6, lr = lane & 15, lg = lane >> 4;
  const int wrow = (wid >> 1) << 6, wcol = (wid & 1) << 6;
#pragma unroll
  for (int mi = 0; mi < 4; ++mi)
#pragma unroll
    for (int ni = 0; ni < 4; ++ni)
#pragma unroll
      for (int j = 0; j < 4; ++j) {
        int rt = rt0 + wrow + mi * 16 + lg * 4 + j;
        int d = c0 + wcol + ni * 16 + lr;
        out[(size_t)rt * 1024 + d] = acc[mi][ni][j] + bsum[d];
      }
}

// ------------------------------------------------------------------ launch -
extern "C" void kernel_launch(void* const* d_in, const int* in_sizes, int n_in,
                              void* d_out, int out_size, void* d_ws,
                              size_t ws_size, hipStream_t stream) {
  (void)in_sizes; (void)n_in; (void)out_size; (void)ws_size;
  const float* x  = (const float*)d_in[0];
  const float* Wq = (const float*)d_in[2];
  const float* Wk = (const float*)d_in[3];
  const float* Wv = (const float*)d_in[4];
  const float* Wo = (const float*)d_in[5];
  const float* bq = (const float*)d_in[6];
  const float* bk = (const float*)d_in[7];
  const float* bv = (const float*)d_in[8];
  const float* bo = (const float*)d_in[9];

  char* w = (char*)d_ws;
  u16* xb  = (u16*)(w);                     // 8 MB (reused as ctx)
  u16* ctx = (u16*)(w);
  u16* qb  = (u16*)(w + (8ull << 20));      // 8 MB (Q pre-scaled by 0.125*log2e)
  u16* kbb = (u16*)(w + (16ull << 20));     // 8 MB  K blocked
  u16* vbb = (u16*)(w + (24ull << 20));     // 8 MB  V blocked
  u16* wT  = (u16*)(w + (32ull << 20));     // 6 MB  [3][hf][d]
  u16* woT = (u16*)(w + (38ull << 20));     // 2 MB  [d][hf]
  float* bqkv = (float*)(w + (40ull << 20));
  float* bsum = (float*)(w + (40ull << 20) + (12u << 10));
  float* out = (float*)d_out;

  prep_all<<<dim3(16, 16, 4), 256, 0, stream>>>(
      (const float4*)x, (uint2*)xb, Wq, Wk, Wv, Wo, bq, bk, bv, bo, wT, woT,
      bqkv, bsum);
  qkv_gemm<<<dim3(32, 8, 3), 256, 0, stream>>>(xb, wT, bqkv, qb, kbb, vbb);
  attn_kernel<<<dim3(16, 32), 256, 0, stream>>>(qb, kbb, vbb, ctx);
  out_gemm<<<dim3(32, 8), 256, 0, stream>>>(ctx, woT, bsum, out);
}

// Round 21
// 121.492 us; speedup vs baseline: 1.0136x; 1.0120x over previous
//
#include <hip/hip_runtime.h>

typedef unsigned short u16;
typedef unsigned int u32;
typedef __bf16 bf16x8 __attribute__((ext_vector_type(8)));
typedef float f32x4 __attribute__((ext_vector_type(4)));
typedef float f32x16 __attribute__((ext_vector_type(16)));

#define QSCALE 0.18033688011112042f /* 0.125 * log2(e) */

__device__ __forceinline__ u16 f2bf(float f) {
  union { float f; unsigned int u; } v;
  v.f = f;
  unsigned int r = v.u + 0x7fffu + ((v.u >> 16) & 1u);
  return (u16)(r >> 16);
}

__device__ __forceinline__ u32 pack2bf(float lo, float hi) {
  __bf16 a = (__bf16)lo, b = (__bf16)hi;
  return (u32)__builtin_bit_cast(u16, a) | ((u32)__builtin_bit_cast(u16, b) << 16);
}

__device__ __forceinline__ float fexp2(float x) {
#if __has_builtin(__builtin_amdgcn_exp2f)
  return __builtin_amdgcn_exp2f(x);
#else
  return __builtin_exp2f(x);
#endif
}

__device__ __forceinline__ f32x4 mfma16(bf16x8 a, bf16x8 b, f32x4 c) {
  return __builtin_amdgcn_mfma_f32_16x16x32_bf16(a, b, c, 0, 0, 0);
}
__device__ __forceinline__ f32x16 mfma32(bf16x8 a, bf16x8 b, f32x16 c) {
  return __builtin_amdgcn_mfma_f32_32x32x16_bf16(a, b, c, 0, 0, 0);
}

// async global->LDS, 16B per lane; lds base must be wave-uniform.
__device__ __forceinline__ void gl_lds16(const u16* g, u16* l) {
  __builtin_amdgcn_global_load_lds(
      (const __attribute__((address_space(1))) u32*)(const void*)g,
      (__attribute__((address_space(3))) u32*)(void*)l, 16, 0, 0);
}

#define ZERO16 {0.f,0.f,0.f,0.f,0.f,0.f,0.f,0.f,0.f,0.f,0.f,0.f,0.f,0.f,0.f,0.f}

// ---------------------------------------------------------------- prep ----
// Fused: every block casts 1/1024 of x (1024 float4 each) -> bf16, then does
// its weight tile. z: 0..2 -> Wq/Wk/Wv, 3 -> Wo (+bias).
__global__ __launch_bounds__(256) void prep_all(
    const float4* __restrict__ x4, uint2* __restrict__ xb2,
    const float* __restrict__ Wq, const float* __restrict__ Wk,
    const float* __restrict__ Wv, const float* __restrict__ Wo,
    const float* __restrict__ bq, const float* __restrict__ bk,
    const float* __restrict__ bv, const float* __restrict__ bo,
    u16* __restrict__ wT, u16* __restrict__ woT, float* __restrict__ bqkv,
    float* __restrict__ bsum) {
  __shared__ u16 tile[64][72];
  const int tid = threadIdx.x;
  const int z = blockIdx.z;
  const int h = blockIdx.x;
  const int d0 = blockIdx.y * 64;
  {
    int bid = (z * 16 + blockIdx.y) * 16 + blockIdx.x;
    int base = bid * 1024 + tid;
#pragma unroll
    for (int k = 0; k < 4; ++k) {
      int i = base + k * 256;
      float4 v = x4[i];
      xb2[i] = make_uint2(pack2bf(v.x, v.y), pack2bf(v.z, v.w));
    }
  }
  if (z < 3) {
    const float* W = (z == 0) ? Wq : ((z == 1) ? Wk : Wv);
    const float scale = (z == 0) ? QSCALE : 1.0f;
#pragma unroll
    for (int p = 0; p < 16; ++p) {
      int idx = p * 256 + tid;
      int r = idx >> 6, f = idx & 63;
      tile[f][r] = f2bf(W[(size_t)h * 65536 + (size_t)(d0 + r) * 64 + f] * scale);
    }
    __syncthreads();
#pragma unroll
    for (int p = 0; p < 4; ++p) {
      int idx = p * 256 + tid;
      int f = idx >> 4, c4 = (idx & 15) * 4;
      *(uint2*)(wT + (size_t)z * 1048576 + (size_t)(h * 64 + f) * 1024 + d0 + c4) =
          *(const uint2*)&tile[f][c4];
    }
  } else {
#pragma unroll
    for (int p = 0; p < 16; ++p) {
      int idx = p * 256 + tid;
      int r = idx >> 6, cc = idx & 63;
      tile[cc][r] = f2bf(Wo[(size_t)(h * 64 + r) * 1024 + d0 + cc]);
    }
    __syncthreads();
#pragma unroll
    for (int p = 0; p < 4; ++p) {
      int idx = p * 256 + tid;
      int dr = idx >> 4, c4 = (idx & 15) * 4;
      *(uint2*)(woT + (size_t)(d0 + dr) * 1024 + h * 64 + c4) =
          *(const uint2*)&tile[dr][c4];
    }
    if (h == 0 && blockIdx.y == 0) {
      for (int i = tid; i < 1024; i += 256) {
        float s = 0.f;
        for (int hh = 0; hh < 16; ++hh) s += bo[hh * 1024 + i];
        bsum[i] = s;
        bqkv[i] = bq[i] * QSCALE;
        bqkv[1024 + i] = bk[i];
        bqkv[2048 + i] = bv[i];
      }
    }
  }
}

// ------------------------------------------------------------- GEMM core ---
__device__ __forceinline__ void gemm_main(const u16* __restrict__ A,
                                          const u16* __restrict__ B,
                                          f32x4 acc[4][4], u16* la, u16* lb,
                                          int tid) {
  const int lane = tid & 63;
  const int wid = tid >> 6;
  const int lr = lane & 15;
  const int lg = lane >> 4;
  const int wrow = (wid >> 1) << 6;
  const int wcol = (wid & 1) << 6;
  const int swz = lr & 7;
  for (int k0 = 0; k0 < 1024; k0 += 64) {
#pragma unroll
    for (int p = 0; p < 4; ++p) {
      int gs = p * 256 + tid;
      int row = gs >> 3;
      int col = ((tid & 7) ^ (row & 7)) * 8;
      gl_lds16(A + (size_t)row * 1024 + k0 + col, la + (p * 4 + wid) * 512);
      gl_lds16(B + (size_t)row * 1024 + k0 + col, lb + (p * 4 + wid) * 512);
    }
    __syncthreads();
#pragma unroll
    for (int kk = 0; kk < 2; ++kk) {
      const int so = ((kk * 4 + lg) ^ swz) << 3;
      bf16x8 af[4], bfr[4];
#pragma unroll
      for (int i = 0; i < 4; ++i) {
        af[i] = *(const bf16x8*)(la + (wrow + i * 16 + lr) * 64 + so);
        bfr[i] = *(const bf16x8*)(lb + (wcol + i * 16 + lr) * 64 + so);
      }
      __builtin_amdgcn_s_setprio(1);
#pragma unroll
      for (int mi = 0; mi < 4; ++mi)
#pragma unroll
        for (int ni = 0; ni < 4; ++ni)
          acc[mi][ni] = mfma16(af[mi], bfr[ni], acc[mi][ni]);
      __builtin_amdgcn_s_setprio(0);
    }
    __syncthreads();
  }
}

// --------------------------------------------------------------- QKV GEMM --
// XCD-aware swizzle (kept from R20; neutral but harmless).
__global__ __launch_bounds__(256) void qkv_gemm(
    const u16* __restrict__ xb, const u16* __restrict__ wT,
    const float* __restrict__ bqkv, u16* __restrict__ qb, u16* __restrict__ kbb,
    u16* __restrict__ vbb) {
  __shared__ __align__(16) u16 lsh[16384];  // 32 KB: GEMM staging, then tile
  const int tid = threadIdx.x;
  const int mm = blockIdx.z;
  const int lin = blockIdx.y * 32 + blockIdx.x;  // 0..255
  const int xcd = lin & 7;
  const int s = lin >> 3;            // 0..31
  const int bx = xcd * 4 + (s & 3);  // row-tile 0..31
  const int by = s >> 2;             // col-tile 0..7
  const u16* Abase;
  const u16* Bbase;
  if (mm == 2) {  // V: compute C^T (rows = hf, cols = t)
    Abase = wT + 2u * 1048576 + (size_t)(by * 128) * 1024;
    Bbase = xb + (size_t)(bx * 128) * 1024;
  } else {
    Abase = xb + (size_t)(bx * 128) * 1024;
    Bbase = wT + (size_t)mm * 1048576 + (size_t)(by * 128) * 1024;
  }
  f32x4 acc[4][4];
#pragma unroll
  for (int mi = 0; mi < 4; ++mi)
#pragma unroll
    for (int ni = 0; ni < 4; ++ni) acc[mi][ni] = (f32x4){0.f, 0.f, 0.f, 0.f};
  gemm_main(Abase, Bbase, acc, lsh, lsh + 8192, tid);
  const int lane = tid & 63, wid = tid >> 6, lr = lane & 15, lg = lane >> 4;
  const int wrow = (wid >> 1) << 6, wcol = (wid & 1) << 6;
  if (mm != 2) {
    // Q and K: rows = t, cols = hf. Stage [t_loc][hf chunks swizzled].
#pragma unroll
    for (int mi = 0; mi < 4; ++mi)
#pragma unroll
      for (int ni = 0; ni < 4; ++ni)
#pragma unroll
        for (int j = 0; j < 4; ++j) {
          int t_loc = wrow + mi * 16 + lg * 4 + j;
          int hf_loc = wcol + ni * 16 + lr;
          float v = acc[mi][ni][j] + bqkv[mm * 1024 + by * 128 + hf_loc];
          int ch = hf_loc >> 3, off = hf_loc & 7;
          lsh[t_loc * 128 + (((ch & 8) | ((ch ^ t_loc) & 7)) << 3) + off] =
              f2bf(v);
        }
    __syncthreads();
    const int t0g = bx * 128;
    if (mm == 0) {
#pragma unroll
      for (int p = 0; p < 8; ++p) {
        int o = p * 256 + tid;  // t_loc(7) hh(1) fc(3)
        int fc = o & 7, hh = (o >> 3) & 1, t_loc = o >> 4;
        int ch = hh * 8 + fc;
        uint4 val = *(const uint4*)&lsh[t_loc * 128 +
                                        (((ch & 8) | ((ch ^ t_loc) & 7)) << 3)];
        int t = t0g + t_loc;
        int b = t >> 11, tt = t & 2047;
        size_t bh = (size_t)(b * 16 + by * 2 + hh);
        *(uint4*)&qb[(bh * 2048 + tt) * 64 + fc * 8] = val;
      }
    } else {
#pragma unroll
      for (int p = 0; p < 8; ++p) {
        int o = p * 256 + tid;  // hh(1) dc(3) t_loc(7)
        int t_loc = o & 127, dc = (o >> 7) & 7, hh = o >> 10;
        int ch = hh * 8 + dc;
        uint4 val = *(const uint4*)&lsh[t_loc * 128 +
                                        (((ch & 8) | ((ch ^ t_loc) & 7)) << 3)];
        int t = t0g + t_loc;
        int b = t >> 11, tt = t & 2047;
        size_t bh = (size_t)(b * 16 + by * 2 + hh);
        *(uint4*)&kbb[bh * 131072 + (size_t)(tt >> 6) * 4096 + dc * 512 +
                      (tt & 63) * 8] = val;
      }
    }
  } else {
    // V: rows hf, cols t; stage [hf_loc][t chunks swizzled]
#pragma unroll
    for (int mi = 0; mi < 4; ++mi)
#pragma unroll
      for (int ni = 0; ni < 4; ++ni)
#pragma unroll
        for (int j = 0; j < 4; ++j) {
          int hf_loc = wrow + mi * 16 + lg * 4 + j;
          int t_loc = wcol + ni * 16 + lr;
          float v = acc[mi][ni][j] + bqkv[2048 + by * 128 + hf_loc];
          int tch = t_loc >> 3, off = t_loc & 7;
          lsh[hf_loc * 128 + (((tch & 8) | ((tch ^ hf_loc) & 7)) << 3) + off] =
              f2bf(v);
        }
    __syncthreads();
    const int tcol0 = bx * 128;
#pragma unroll
    for (int p = 0; p < 8; ++p) {
      int o = p * 256 + tid;  // hh(1) tb(1) sc(3) f(6)
      int f = o & 63, sc = (o >> 6) & 7, tb = (o >> 9) & 1, hh = o >> 10;
      int hf_loc = hh * 64 + f;
      int tch = tb * 8 + sc;
      uint4 val = *(const uint4*)&lsh[hf_loc * 128 +
                                      (((tch & 8) | ((tch ^ hf_loc) & 7)) << 3)];
      int t = tcol0 + tch * 8;
      int b = t >> 11, tt = t & 2047;
      size_t bh = (size_t)(b * 16 + by * 2 + hh);
      *(uint4*)&vbb[bh * 131072 + (size_t)(tt >> 6) * 4096 +
                    ((tt >> 3) & 7) * 512 + f * 8] = val;
    }
  }
}

// --------------------------------------------------------------- attention -
// R18 structure with PAIRED tiles per barrier: 4 LDS buffers (64 KB), stage
// tiles (2j+2, 2j+3) while computing (2j, 2j+1); ONE __syncthreads per pair
// (16 barriers instead of 32, 2x latency cover per stage).
// exp2-direct softmax, VALU lsum + post shfl, permlane32_swap PV exchange.
#define PV_GROUP(A0, A1, B0, B1, VF0, VF1)                                    \
  {                                                                           \
    u32 xa = (A0), xb_ = (B0), ya = (A1), yb = (B1);                          \
    asm("v_permlane32_swap_b32 %0, %1" : "+v"(xa), "+v"(xb_));                \
    asm("v_permlane32_swap_b32 %0, %1" : "+v"(ya), "+v"(yb));                 \
    uint4 wv = make_uint4(xa, ya, xb_, yb);                                   \
    bf16x8 pf = __builtin_bit_cast(bf16x8, wv);                               \
    acc0 = mfma32((VF0), pf, acc0);                                           \
    acc1 = mfma32((VF1), pf, acc1);                                           \
  }

__device__ __forceinline__ void attn_tile(const u16* __restrict__ kbuf,
                                          const u16* __restrict__ vbuf,
                                          bf16x8 (&qf)[4], float& lsum,
                                          f32x16& acc0, f32x16& acc1, int c,
                                          int hi) {
  bf16x8 kA[4], kB[4], vA[4], vB[4];
#pragma unroll
  for (int kki = 0; kki < 4; ++kki) {
    kA[kki] = *(const bf16x8*)(kbuf + (kki * 2 + hi) * 512 + c * 8);
    kB[kki] = *(const bf16x8*)(kbuf + (kki * 2 + hi) * 512 + 256 + c * 8);
  }
#pragma unroll
  for (int g = 0; g < 4; ++g) {
    vA[g] = *(const bf16x8*)(vbuf + (g * 2 + hi) * 512 + c * 8);
    vB[g] = *(const bf16x8*)(vbuf + (g * 2 + hi) * 512 + 256 + c * 8);
  }
  f32x16 sA = ZERO16, sB = ZERO16;
  __builtin_amdgcn_s_setprio(1);
#pragma unroll
  for (int kki = 0; kki < 4; ++kki) {
    sA = mfma32(kA[kki], qf[kki], sA);
    sB = mfma32(kB[kki], qf[kki], sB);
  }
  __builtin_amdgcn_s_setprio(0);
  float a0 = fexp2(sA[0]), a1 = fexp2(sA[1]);
  float a2 = fexp2(sA[2]), a3 = fexp2(sA[3]);
  float a4 = fexp2(sA[4]), a5 = fexp2(sA[5]);
  float a6 = fexp2(sA[6]), a7 = fexp2(sA[7]);
  float a8 = fexp2(sA[8]), a9 = fexp2(sA[9]);
  float a10 = fexp2(sA[10]), a11 = fexp2(sA[11]);
  float a12 = fexp2(sA[12]), a13 = fexp2(sA[13]);
  float a14 = fexp2(sA[14]), a15 = fexp2(sA[15]);
  float b0 = fexp2(sB[0]), b1 = fexp2(sB[1]);
  float b2 = fexp2(sB[2]), b3 = fexp2(sB[3]);
  float b4 = fexp2(sB[4]), b5 = fexp2(sB[5]);
  float b6 = fexp2(sB[6]), b7 = fexp2(sB[7]);
  float b8 = fexp2(sB[8]), b9 = fexp2(sB[9]);
  float b10 = fexp2(sB[10]), b11 = fexp2(sB[11]);
  float b12 = fexp2(sB[12]), b13 = fexp2(sB[13]);
  float b14 = fexp2(sB[14]), b15 = fexp2(sB[15]);
  float sa = (((a0 + a1) + (a2 + a3)) + ((a4 + a5) + (a6 + a7))) +
             (((a8 + a9) + (a10 + a11)) + ((a12 + a13) + (a14 + a15)));
  float sb = (((b0 + b1) + (b2 + b3)) + ((b4 + b5) + (b6 + b7))) +
             (((b8 + b9) + (b10 + b11)) + ((b12 + b13) + (b14 + b15)));
  lsum += sa + sb;
  u32 pkA00 = pack2bf(a0, a1), pkA01 = pack2bf(a2, a3);
  u32 pkA10 = pack2bf(a4, a5), pkA11 = pack2bf(a6, a7);
  u32 pkA20 = pack2bf(a8, a9), pkA21 = pack2bf(a10, a11);
  u32 pkA30 = pack2bf(a12, a13), pkA31 = pack2bf(a14, a15);
  u32 pkB00 = pack2bf(b0, b1), pkB01 = pack2bf(b2, b3);
  u32 pkB10 = pack2bf(b4, b5), pkB11 = pack2bf(b6, b7);
  u32 pkB20 = pack2bf(b8, b9), pkB21 = pack2bf(b10, b11);
  u32 pkB30 = pack2bf(b12, b13), pkB31 = pack2bf(b14, b15);
  __builtin_amdgcn_s_setprio(1);
  PV_GROUP(pkA00, pkA01, pkA10, pkA11, vA[0], vB[0])
  PV_GROUP(pkA20, pkA21, pkA30, pkA31, vA[1], vB[1])
  PV_GROUP(pkB00, pkB01, pkB10, pkB11, vA[2], vB[2])
  PV_GROUP(pkB20, pkB21, pkB30, pkB31, vA[3], vB[3])
  __builtin_amdgcn_s_setprio(0);
}

__global__ __launch_bounds__(256, 2) void attn_kernel(
    const u16* __restrict__ qb, const u16* __restrict__ kbb,
    const u16* __restrict__ vbb, u16* __restrict__ ctx) {
  __shared__ __align__(16) u16 kv[4][8192];  // 4 bufs x (K 8KB | V 8KB)
  const int tid = threadIdx.x;
  const int lane = tid & 63;
  const int wid = tid >> 6;  // = wq (0..3)
  const int c = lane & 31;
  const int hi = lane >> 5;
  const int lin = blockIdx.y * 16 + blockIdx.x;  // 0..511
  const int xcd = lin & 7;
  const int rest = lin >> 3;  // 0..63: 4 bh x 16 q-slots per XCD
  const int bh = xcd * 4 + (rest >> 4);
  const int q0w = (rest & 15) * 128 + wid * 32;

  bf16x8 qf[4];
#pragma unroll
  for (int kki = 0; kki < 4; ++kki)
    qf[kki] = *(const bf16x8*)(qb + ((size_t)(bh * 2048 + q0w + c)) * 64 +
                               kki * 16 + hi * 8);

  const u16* kb_ = kbb + (size_t)bh * 131072;
  const u16* vb_ = vbb + (size_t)bh * 131072;

  f32x16 acc0 = ZERO16, acc1 = ZERO16;
  float lsum = 0.f;

#define STAGE(BUF, IT)                                                        \
  {                                                                           \
    const u16* bk = kb_ + (IT) * 4096;                                        \
    const u16* bv = vb_ + (IT) * 4096;                                        \
    _Pragma("unroll") for (int p = 0; p < 2; ++p) {                           \
      int ch = (p * 4 + wid) * 64 + lane;                                     \
      gl_lds16(bk + ch * 8, &kv[BUF][(p * 4 + wid) * 512]);                   \
      gl_lds16(bv + ch * 8, &kv[BUF][4096 + (p * 4 + wid) * 512]);            \
    }                                                                         \
  }

  STAGE(0, 0)
  STAGE(1, 1)
  __syncthreads();

  for (int j = 0; j < 16; ++j) {
    const int base = (j & 1) * 2;   // resident pair
    const int other = 2 - base;     // pair being staged
    if (j < 15) {
      STAGE(other, 2 * j + 2)
      STAGE(other + 1, 2 * j + 3)
    }
    attn_tile(&kv[base][0], &kv[base][4096], qf, lsum, acc0, acc1, c, hi);
    attn_tile(&kv[base + 1][0], &kv[base + 1][4096], qf, lsum, acc0, acc1, c,
              hi);
    __syncthreads();
  }
  lsum += __shfl_xor(lsum, 32, 64);
  float invl = 1.0f / lsum;

  // ---- epilogue: normalize, transpose ctx^T -> ctx via per-wave LDS scratch
  u16* scr = &kv[0][0] + wid * 2048;
#pragma unroll
  for (int g = 0; g < 8; ++g) {
    int f0 = 2 * (g & 1) + 8 * (g >> 1) + 4 * hi;
    *(u32*)(scr + (((c * 64 + f0) ^ ((c & 7) << 3)))) =
        pack2bf(acc0[2 * g] * invl, acc0[2 * g + 1] * invl);
    *(u32*)(scr + (((c * 64 + f0 + 32) ^ ((c & 7) << 3)))) =
        pack2bf(acc1[2 * g] * invl, acc1[2 * g + 1] * invl);
  }
  const int b = bh >> 4, h = bh & 15;
#pragma unroll
  for (int pass = 0; pass < 4; ++pass) {
    int trow = pass * 8 + (lane >> 3);
    int chunk = lane & 7;
    uint4 val =
        *(const uint4*)(scr + ((trow * 64 + chunk * 8) ^ ((trow & 7) << 3)));
    *(uint4*)(ctx + ((size_t)(b * 2048 + q0w + trow)) * 1024 + h * 64 +
              chunk * 8) = val;
  }
}

// ---------------------------------------------------------------- out GEMM -
__global__ __launch_bounds__(256) void out_gemm(const u16* __restrict__ ctx,
                                                const u16* __restrict__ woT,
                                                const float* __restrict__ bsum,
                                                float* __restrict__ out) {
  __shared__ __align__(16) u16 la[8192];
  __shared__ __align__(16) u16 lb[8192];
  const int tid = threadIdx.x;
  const int lin = blockIdx.y * 32 + blockIdx.x;  // 0..255
  const int xcd = lin & 7;
  const int s = lin >> 3;
  const int bx = xcd * 4 + (s & 3);
  const int by = s >> 2;
  const int rt0 = bx * 128;
  const int c0 = by * 128;
  f32x4 acc[4][4];
#pragma unroll
  for (int mi = 0; mi < 4; ++mi)
#pragma unroll
    for (int ni = 0; ni < 4; ++ni) acc[mi][ni] = (f32x4){0.f, 0.f, 0.f, 0.f};
  gemm_main(ctx + (size_t)rt0 * 1024, woT + (size_t)c0 * 1024, acc, la, lb,
            tid);
  const int lane = tid & 63, wid = tid >> 6, lr = lane & 15, lg = lane >> 4;
  const int wrow = (wid >> 1) << 6, wcol = (wid & 1) << 6;
#pragma unroll
  for (int mi = 0; mi < 4; ++mi)
#pragma unroll
    for (int ni = 0; ni < 4; ++ni)
#pragma unroll
      for (int j = 0; j < 4; ++j) {
        int rt = rt0 + wrow + mi * 16 + lg * 4 + j;
        int d = c0 + wcol + ni * 16 + lr;
        out[(size_t)rt * 1024 + d] = acc[mi][ni][j] + bsum[d];
      }
}

// ------------------------------------------------------------------ launch -
extern "C" void kernel_launch(void* const* d_in, const int* in_sizes, int n_in,
                              void* d_out, int out_size, void* d_ws,
                              size_t ws_size, hipStream_t stream) {
  (void)in_sizes; (void)n_in; (void)out_size; (void)ws_size;
  const float* x  = (const float*)d_in[0];
  const float* Wq = (const float*)d_in[2];
  const float* Wk = (const float*)d_in[3];
  const float* Wv = (const float*)d_in[4];
  const float* Wo = (const float*)d_in[5];
  const float* bq = (const float*)d_in[6];
  const float* bk = (const float*)d_in[7];
  const float* bv = (const float*)d_in[8];
  const float* bo = (const float*)d_in[9];

  char* w = (char*)d_ws;
  u16* xb  = (u16*)(w);                     // 8 MB (reused as ctx)
  u16* ctx = (u16*)(w);
  u16* qb  = (u16*)(w + (8ull << 20));      // 8 MB (Q pre-scaled by 0.125*log2e)
  u16* kbb = (u16*)(w + (16ull << 20));     // 8 MB  K blocked
  u16* vbb = (u16*)(w + (24ull << 20));     // 8 MB  V blocked
  u16* wT  = (u16*)(w + (32ull << 20));     // 6 MB  [3][hf][d]
  u16* woT = (u16*)(w + (38ull << 20));     // 2 MB  [d][hf]
  float* bqkv = (float*)(w + (40ull << 20));
  float* bsum = (float*)(w + (40ull << 20) + (12u << 10));
  float* out = (float*)d_out;

  prep_all<<<dim3(16, 16, 4), 256, 0, stream>>>(
      (const float4*)x, (uint2*)xb, Wq, Wk, Wv, Wo, bq, bk, bv, bo, wT, woT,
      bqkv, bsum);
  qkv_gemm<<<dim3(32, 8, 3), 256, 0, stream>>>(xb, wT, bqkv, qb, kbb, vbb);
  attn_kernel<<<dim3(16, 32), 256, 0, stream>>>(qb, kbb, vbb, ctx);
  out_gemm<<<dim3(32, 8), 256, 0, stream>>>(ctx, woT, bsum, out);
}